// Round 2
// baseline (623.480 us; speedup 1.0000x reference)
//
#include <hip/hip_runtime.h>
#include <math.h>

#define HW   9216
#define WIMG 96
#define NPIX 73728  // 8 * 9216
#define CIN  256
#define CO   128

// ---------------------------------------------------------------------------
// K1: per-pixel features  theta/phi/g = W . x[pixel] + b   (pixel-major out)
// grid: NPIX/32 blocks x 256 threads. LDS: 32 pixels x 256 ch = 32KB.
// thread: pg = t&7 (4 pixels), og = t>>3 (3 chunks of 4 outputs: f0=og*12+kk*4)
// Weights loaded as float4 along c (dwordx4 from L1) — not per-c scalars.
// ---------------------------------------------------------------------------
__global__ __launch_bounds__(256) void k_features(
    const float* __restrict__ x,
    const float* __restrict__ wt, const float* __restrict__ bt,
    const float* __restrict__ wp, const float* __restrict__ bp,
    const float* __restrict__ wg, const float* __restrict__ bg,
    float* __restrict__ th, float* __restrict__ ph, float* __restrict__ gf)
{
    __shared__ float xs[CIN * 32];
    const int t  = threadIdx.x;
    const int P0 = blockIdx.x * 32;        // block never straddles batch: 9216%32==0
    const int b  = P0 / HW;
    const int p0 = P0 - b * HW;
    const float* xb = x + (size_t)b * CIN * HW + p0;

    #pragma unroll
    for (int k = 0; k < 32; ++k) {         // 8192 floats / 256 threads
        int idx = t + k * 256;
        int c = idx >> 5, p = idx & 31;
        xs[idx] = xb[(size_t)c * HW + p];
    }
    __syncthreads();

    const int pg = t & 7;                  // pixel group: pixels pg*4 .. pg*4+3
    const int og = t >> 3;                 // 0..31

    #pragma unroll
    for (int kk = 0; kk < 3; ++kk) {
        const int f0 = og * 12 + kk * 4;   // multiples of 4, never straddles a matrix
        const int m  = f0 >> 7;            // 0=theta 1=phi 2=g
        const int r  = f0 & 127;
        const float* Wsel = (m == 0) ? wt : ((m == 1) ? wp : wg);
        const float* Bsel = (m == 0) ? bt : ((m == 1) ? bp : bg);
        float*       Osel = (m == 0) ? th : ((m == 1) ? ph : gf);
        const float* w0 = Wsel + (size_t)r * CIN;
        const float* w1 = w0 + CIN;
        const float* w2 = w1 + CIN;
        const float* w3 = w2 + CIN;

        float acc[4][4];
        #pragma unroll
        for (int i = 0; i < 4; ++i)
            #pragma unroll
            for (int j = 0; j < 4; ++j) acc[i][j] = 0.f;

        #pragma unroll 2
        for (int c4 = 0; c4 < CIN; c4 += 4) {
            float4 a0 = *(const float4*)(w0 + c4);
            float4 a1 = *(const float4*)(w1 + c4);
            float4 a2 = *(const float4*)(w2 + c4);
            float4 a3 = *(const float4*)(w3 + c4);
            float wrow[4][4] = {{a0.x, a0.y, a0.z, a0.w},
                                {a1.x, a1.y, a1.z, a1.w},
                                {a2.x, a2.y, a2.z, a2.w},
                                {a3.x, a3.y, a3.z, a3.w}};
            #pragma unroll
            for (int cc = 0; cc < 4; ++cc) {
                float4 xv = *(const float4*)(xs + (c4 + cc) * 32 + pg * 4);
                float xvv[4] = {xv.x, xv.y, xv.z, xv.w};
                #pragma unroll
                for (int i = 0; i < 4; ++i)
                    #pragma unroll
                    for (int j = 0; j < 4; ++j)
                        acc[i][j] = fmaf(xvv[i], wrow[j][cc], acc[i][j]);
            }
        }

        float4 bias = *(const float4*)(Bsel + r);
        float bb4[4] = {bias.x, bias.y, bias.z, bias.w};
        #pragma unroll
        for (int i = 0; i < 4; ++i) {
            size_t row = ((size_t)(P0 + pg * 4 + i)) * CO + r;
            float4 o4;
            o4.x = acc[i][0] + bb4[0];
            o4.y = acc[i][1] + bb4[1];
            o4.z = acc[i][2] + bb4[2];
            o4.w = acc[i][3] + bb4[3];
            *(float4*)(Osel + row) = o4;
        }
    }
}

// ---------------------------------------------------------------------------
// K2: cosine-sim attention over 9 neighbors + weighted avg of g -> wa
// 4 lanes per pixel (32 ch each), shfl_xor(1,2) quad reductions.
// th and wa may alias (theta[P] read only by pixel P's quad, fully before
// the wa[P] store) -> no __restrict__ on those two.
// ---------------------------------------------------------------------------
__global__ __launch_bounds__(256) void k_attn(
    const float* th, const float* __restrict__ ph,
    const float* __restrict__ gf, float* wa)
{
    const int t = threadIdx.x;
    const int s = t >> 2, q = t & 3;
    const int P = blockIdx.x * 64 + s;
    const int b = P / HW;
    const int p = P - b * HW;
    const int h = p / WIMG;
    const int w = p - h * WIMG;
    const size_t ib = (size_t)b * HW;

    const float* tv = th + (size_t)P * CO + q * 32;
    float4 T[8];
    #pragma unroll
    for (int j = 0; j < 8; ++j) T[j] = *(const float4*)(tv + j * 4);

    float tt = 0.f;
    #pragma unroll
    for (int j = 0; j < 8; ++j)
        tt += T[j].x * T[j].x + T[j].y * T[j].y + T[j].z * T[j].z + T[j].w * T[j].w;
    tt += __shfl_xor(tt, 1);
    tt += __shfl_xor(tt, 2);
    const float st = sqrtf(tt);

    float score[9];
    #pragma unroll
    for (int n = 0; n < 9; ++n) {
        int hh = h + n / 3 - 1; hh = hh < 0 ? 0 : (hh > 95 ? 95 : hh);
        int w2 = w + n % 3 - 1; w2 = w2 < 0 ? 0 : (w2 > 95 ? 95 : w2);
        const float* pv = ph + (ib + hh * WIMG + w2) * CO + q * 32;
        float d = 0.f, pp = 0.f;
        #pragma unroll
        for (int j = 0; j < 8; ++j) {
            float4 v = *(const float4*)(pv + j * 4);
            d  += T[j].x * v.x + T[j].y * v.y + T[j].z * v.z + T[j].w * v.w;
            pp += v.x * v.x + v.y * v.y + v.z * v.z + v.w * v.w;
        }
        d  += __shfl_xor(d, 1);  d  += __shfl_xor(d, 2);
        pp += __shfl_xor(pp, 1); pp += __shfl_xor(pp, 2);
        float den = fmaxf(sqrtf(pp) * st, 1e-8f);
        score[n] = d / den;
    }

    float mx = score[0];
    #pragma unroll
    for (int n = 1; n < 9; ++n) mx = fmaxf(mx, score[n]);
    float sum = 0.f;
    #pragma unroll
    for (int n = 0; n < 9; ++n) { score[n] = expf(score[n] - mx); sum += score[n]; }
    const float inv = 1.f / sum;

    float4 acc[8];
    #pragma unroll
    for (int j = 0; j < 8; ++j) acc[j] = make_float4(0.f, 0.f, 0.f, 0.f);

    #pragma unroll
    for (int n = 0; n < 9; ++n) {
        int hh = h + n / 3 - 1; hh = hh < 0 ? 0 : (hh > 95 ? 95 : hh);
        int w2 = w + n % 3 - 1; w2 = w2 < 0 ? 0 : (w2 > 95 ? 95 : w2);
        const float* gv = gf + (ib + hh * WIMG + w2) * CO + q * 32;
        float a = score[n] * inv;
        #pragma unroll
        for (int j = 0; j < 8; ++j) {
            float4 v = *(const float4*)(gv + j * 4);
            acc[j].x = fmaf(a, v.x, acc[j].x);
            acc[j].y = fmaf(a, v.y, acc[j].y);
            acc[j].z = fmaf(a, v.z, acc[j].z);
            acc[j].w = fmaf(a, v.w, acc[j].w);
        }
    }

    float* ov = wa + (size_t)P * CO + q * 32;
    #pragma unroll
    for (int j = 0; j < 8; ++j) *(float4*)(ov + j * 4) = acc[j];
}

// ---------------------------------------------------------------------------
// K3: out = x + wa . w_back^T + b_back   (GEMM M=NPIX, N=256, K=128)
// LDS holds wa tile transposed [o][p] stride 68 (16B-aligned, 8-bank spread).
// ---------------------------------------------------------------------------
__global__ __launch_bounds__(256) void k_back(
    const float* __restrict__ wa, const float* __restrict__ wb,
    const float* __restrict__ bb, const float* __restrict__ x,
    float* __restrict__ out)
{
    __shared__ float was[CO * 68];
    const int t  = threadIdx.x;
    const int P0 = blockIdx.x * 64;        // 9216 % 64 == 0
    const int b  = P0 / HW;
    const int p0 = P0 - b * HW;
    const float* wab = wa + (size_t)P0 * CO;

    #pragma unroll
    for (int k = 0; k < 32; ++k) {         // 8192 floats
        int idx = t + k * 256;
        int p = idx >> 7, o = idx & 127;
        was[o * 68 + p] = wab[idx];
    }
    __syncthreads();

    const int pg = t & 15;                 // 4 pixels
    const int cg = t >> 4;                 // 16 channels in 4 chunks of 4

    #pragma unroll
    for (int kk = 0; kk < 4; ++kk) {
        const int c0 = cg * 16 + kk * 4;
        const float* w0 = wb + (size_t)c0 * CO;
        const float* w1 = w0 + CO;
        const float* w2 = w1 + CO;
        const float* w3 = w2 + CO;

        float acc[4][4];
        #pragma unroll
        for (int i = 0; i < 4; ++i)
            #pragma unroll
            for (int j = 0; j < 4; ++j) acc[i][j] = 0.f;

        #pragma unroll 2
        for (int o4i = 0; o4i < CO; o4i += 4) {
            float4 a0 = *(const float4*)(w0 + o4i);
            float4 a1 = *(const float4*)(w1 + o4i);
            float4 a2 = *(const float4*)(w2 + o4i);
            float4 a3 = *(const float4*)(w3 + o4i);
            float wrow[4][4] = {{a0.x, a0.y, a0.z, a0.w},
                                {a1.x, a1.y, a1.z, a1.w},
                                {a2.x, a2.y, a2.z, a2.w},
                                {a3.x, a3.y, a3.z, a3.w}};
            #pragma unroll
            for (int oo = 0; oo < 4; ++oo) {
                float4 wv = *(const float4*)(was + (o4i + oo) * 68 + pg * 4);
                float wvv[4] = {wv.x, wv.y, wv.z, wv.w};
                #pragma unroll
                for (int i = 0; i < 4; ++i)
                    #pragma unroll
                    for (int j = 0; j < 4; ++j)
                        acc[i][j] = fmaf(wvv[i], wrow[j][oo], acc[i][j]);
            }
        }

        #pragma unroll
        for (int j = 0; j < 4; ++j) {
            int c = c0 + j;
            size_t ob = ((size_t)b * CIN + c) * HW + p0 + pg * 4;
            float4 xv = *(const float4*)(x + ob);
            float bbv = bb[c];
            float4 o4;
            o4.x = xv.x + acc[0][j] + bbv;
            o4.y = xv.y + acc[1][j] + bbv;
            o4.z = xv.z + acc[2][j] + bbv;
            o4.w = xv.w + acc[3][j] + bbv;
            *(float4*)(out + ob) = o4;
        }
    }
}

extern "C" void kernel_launch(void* const* d_in, const int* in_sizes, int n_in,
                              void* d_out, int out_size, void* d_ws, size_t ws_size,
                              hipStream_t stream)
{
    const float* x  = (const float*)d_in[0];
    const float* wt = (const float*)d_in[1];
    const float* bt = (const float*)d_in[2];
    const float* wp = (const float*)d_in[3];
    const float* bp = (const float*)d_in[4];
    const float* wg = (const float*)d_in[5];
    const float* bg = (const float*)d_in[6];
    const float* wb = (const float*)d_in[7];
    const float* bb = (const float*)d_in[8];
    float* out = (float*)d_out;

    const size_t FEAT = (size_t)NPIX * CO;       // 9.4M floats = 37.75MB
    float* th = (float*)d_ws;
    float* ph = th + FEAT;
    float* gf = ph + FEAT;
    // wa: separate buffer if workspace allows (151MB), else alias onto th
    // (safe: theta[P] is read only by pixel P's quad, fully before wa[P] store)
    float* wa = (ws_size >= 4 * FEAT * sizeof(float)) ? (gf + FEAT) : th;

    hipLaunchKernelGGL(k_features, dim3(NPIX / 32), dim3(256), 0, stream,
                       x, wt, bt, wp, bp, wg, bg, th, ph, gf);
    hipLaunchKernelGGL(k_attn, dim3(NPIX / 64), dim3(256), 0, stream,
                       th, ph, gf, wa);
    hipLaunchKernelGGL(k_back, dim3(NPIX / 64), dim3(256), 0, stream,
                       wa, wb, bb, x, out);
}

// Round 3
// 358.482 us; speedup vs baseline: 1.7392x; 1.7392x over previous
//
#include <hip/hip_runtime.h>
#include <hip/hip_bf16.h>
#include <math.h>

#define HW   9216
#define WIMG 96
#define NPIX 73728  // 8 * 9216
#define CIN  256
#define CO   128

typedef __attribute__((ext_vector_type(8))) short short8v;   // 8 bf16 (4 VGPR)
typedef __attribute__((ext_vector_type(4))) float f32x4;     // MFMA acc

__device__ __forceinline__ unsigned short f2bf(float f) {
    __hip_bfloat16 h = __float2bfloat16(f);
    return __builtin_bit_cast(unsigned short, h);
}

// Swizzled byte offset into a [rows][64] bf16 LDS tile (128B rows).
// XOR of row bits into the 16B-slot index: rows 0..7 -> distinct slots,
// 16-lane fragment reads are <=2-way (free, m136).
__device__ __forceinline__ int swz(int row, int kk2 /*byte in row*/) {
    return (row * 128 + kk2) ^ ((row & 7) << 4);
}

// ---------------------------------------------------------------------------
// K1 (MFMA): th/ph/gf[pixel][128] = bf16( x[pixel][:] ) . bf16(W^T) + b
// 128x128 tile, BK=64, 4 waves (2x2), 16x16x32 bf16 MFMA.
// grid (NPIX/128, 3): blockIdx.y selects theta/phi/g (each exactly 128 outs).
// A = x (channel-major global -> transposed into LDS [px][k] bf16, swizzled)
// B = W[n][k] row-major ("B^T input", ladder-verified fragment layout)
// ---------------------------------------------------------------------------
__global__ __launch_bounds__(256) void k1_mfma(
    const float* __restrict__ x,
    const float* __restrict__ wt, const float* __restrict__ bt,
    const float* __restrict__ wp, const float* __restrict__ bp,
    const float* __restrict__ wg, const float* __restrict__ bg,
    float* __restrict__ th, float* __restrict__ ph, float* __restrict__ gf)
{
    __shared__ char As[128 * 128];  // [128 px][64 k] bf16, swizzled (16KB)
    __shared__ char Bs[128 * 128];  // [128 n ][64 k] bf16, swizzled (16KB)

    const int t  = threadIdx.x;
    const int nb = blockIdx.y;
    const float* W  = (nb == 0) ? wt : (nb == 1) ? wp : wg;
    const float* Bv = (nb == 0) ? bt : (nb == 1) ? bp : bg;
    float*       O  = (nb == 0) ? th : (nb == 1) ? ph : gf;

    const int P0 = blockIdx.x * 128;       // 9216 % 128 == 0: no batch straddle
    const int b  = P0 / HW;
    const int p0 = P0 - b * HW;
    const float* xb = x + (size_t)b * CIN * HW + p0;

    const int wid = t >> 6, lane = t & 63;
    const int wm = (wid & 1) * 64, wn = (wid >> 1) * 64;
    const int l15 = lane & 15, lg = lane >> 4;

    f32x4 acc[4][4] = {};

    for (int kt = 0; kt < CIN; kt += 64) {
        if (kt) __syncthreads();
        // ---- stage A: x[kt+k][P0+pp] -> As[pp][k]  (transpose + cvt) ----
        // lanes: t&15 -> consecutive pixels (64B-coalesced scalar loads);
        // writes: consecutive lanes -> consecutive rows -> swizzle spreads.
        #pragma unroll
        for (int it = 0; it < 8; ++it) {
            int kq = ((t >> 4) & 3) + (it & 3) * 4;                  // 0..15
            int pp = (t & 15) + ((t >> 6) << 4) + ((it >> 2) << 6);  // 0..127
            ushort4 v;
            v.x = f2bf(xb[(size_t)(kt + kq * 4 + 0) * HW + pp]);
            v.y = f2bf(xb[(size_t)(kt + kq * 4 + 1) * HW + pp]);
            v.z = f2bf(xb[(size_t)(kt + kq * 4 + 2) * HW + pp]);
            v.w = f2bf(xb[(size_t)(kt + kq * 4 + 3) * HW + pp]);
            *(ushort4*)(As + swz(pp, kq * 8)) = v;
        }
        // ---- stage B: W[n][kt+k] -> Bs[n][k] (row-major, float4 loads) ----
        // 16 lanes span one row (256B coalesced); writes 128B/row: conflict-free.
        #pragma unroll
        for (int it = 0; it < 8; ++it) {
            int kq = t & 15;
            int n  = (t >> 4) + it * 16;
            float4 w4 = *(const float4*)(W + (size_t)n * CIN + kt + kq * 4);
            ushort4 v;
            v.x = f2bf(w4.x); v.y = f2bf(w4.y); v.z = f2bf(w4.z); v.w = f2bf(w4.w);
            *(ushort4*)(Bs + swz(n, kq * 8)) = v;
        }
        __syncthreads();
        // ---- compute: 2 k-slices of 32 ----
        #pragma unroll
        for (int ks = 0; ks < 2; ++ks) {
            const int kk2 = ks * 64 + lg * 16;
            short8v a[4], bq[4];
            #pragma unroll
            for (int mt = 0; mt < 4; ++mt)
                a[mt] = *(const short8v*)(As + swz(wm + mt * 16 + l15, kk2));
            #pragma unroll
            for (int nt = 0; nt < 4; ++nt)
                bq[nt] = *(const short8v*)(Bs + swz(wn + nt * 16 + l15, kk2));
            #pragma unroll
            for (int mt = 0; mt < 4; ++mt)
                #pragma unroll
                for (int nt = 0; nt < 4; ++nt)
                    acc[mt][nt] = __builtin_amdgcn_mfma_f32_16x16x32_bf16(
                        a[mt], bq[nt], acc[mt][nt], 0, 0, 0);
        }
    }

    // ---- epilogue: D[row=(lg*4+j)][col=l15], add bias, pixel-major store ----
    float bias[4];
    #pragma unroll
    for (int nt = 0; nt < 4; ++nt) bias[nt] = Bv[wn + nt * 16 + l15];
    #pragma unroll
    for (int mt = 0; mt < 4; ++mt)
        #pragma unroll
        for (int j = 0; j < 4; ++j) {
            size_t row = (size_t)(P0 + wm + mt * 16 + lg * 4 + j) * CO;
            #pragma unroll
            for (int nt = 0; nt < 4; ++nt)
                O[row + wn + nt * 16 + l15] = acc[mt][nt][j] + bias[nt];
        }
}

// ---------------------------------------------------------------------------
// K2: cosine-sim attention over 9 neighbors + weighted avg of g -> wa
// (unchanged from R2 — profiled next round now that K1 won't mask it)
// ---------------------------------------------------------------------------
__global__ __launch_bounds__(256) void k_attn(
    const float* th, const float* __restrict__ ph,
    const float* __restrict__ gf, float* wa)
{
    const int t = threadIdx.x;
    const int s = t >> 2, q = t & 3;
    const int P = blockIdx.x * 64 + s;
    const int b = P / HW;
    const int p = P - b * HW;
    const int h = p / WIMG;
    const int w = p - h * WIMG;
    const size_t ib = (size_t)b * HW;

    const float* tv = th + (size_t)P * CO + q * 32;
    float4 T[8];
    #pragma unroll
    for (int j = 0; j < 8; ++j) T[j] = *(const float4*)(tv + j * 4);

    float tt = 0.f;
    #pragma unroll
    for (int j = 0; j < 8; ++j)
        tt += T[j].x * T[j].x + T[j].y * T[j].y + T[j].z * T[j].z + T[j].w * T[j].w;
    tt += __shfl_xor(tt, 1);
    tt += __shfl_xor(tt, 2);
    const float st = sqrtf(tt);

    float score[9];
    #pragma unroll
    for (int n = 0; n < 9; ++n) {
        int hh = h + n / 3 - 1; hh = hh < 0 ? 0 : (hh > 95 ? 95 : hh);
        int w2 = w + n % 3 - 1; w2 = w2 < 0 ? 0 : (w2 > 95 ? 95 : w2);
        const float* pv = ph + (ib + hh * WIMG + w2) * CO + q * 32;
        float d = 0.f, pp = 0.f;
        #pragma unroll
        for (int j = 0; j < 8; ++j) {
            float4 v = *(const float4*)(pv + j * 4);
            d  += T[j].x * v.x + T[j].y * v.y + T[j].z * v.z + T[j].w * v.w;
            pp += v.x * v.x + v.y * v.y + v.z * v.z + v.w * v.w;
        }
        d  += __shfl_xor(d, 1);  d  += __shfl_xor(d, 2);
        pp += __shfl_xor(pp, 1); pp += __shfl_xor(pp, 2);
        float den = fmaxf(sqrtf(pp) * st, 1e-8f);
        score[n] = d / den;
    }

    float mx = score[0];
    #pragma unroll
    for (int n = 1; n < 9; ++n) mx = fmaxf(mx, score[n]);
    float sum = 0.f;
    #pragma unroll
    for (int n = 0; n < 9; ++n) { score[n] = expf(score[n] - mx); sum += score[n]; }
    const float inv = 1.f / sum;

    float4 acc[8];
    #pragma unroll
    for (int j = 0; j < 8; ++j) acc[j] = make_float4(0.f, 0.f, 0.f, 0.f);

    #pragma unroll
    for (int n = 0; n < 9; ++n) {
        int hh = h + n / 3 - 1; hh = hh < 0 ? 0 : (hh > 95 ? 95 : hh);
        int w2 = w + n % 3 - 1; w2 = w2 < 0 ? 0 : (w2 > 95 ? 95 : w2);
        const float* gv = gf + (ib + hh * WIMG + w2) * CO + q * 32;
        float a = score[n] * inv;
        #pragma unroll
        for (int j = 0; j < 8; ++j) {
            float4 v = *(const float4*)(gv + j * 4);
            acc[j].x = fmaf(a, v.x, acc[j].x);
            acc[j].y = fmaf(a, v.y, acc[j].y);
            acc[j].z = fmaf(a, v.z, acc[j].z);
            acc[j].w = fmaf(a, v.w, acc[j].w);
        }
    }

    float* ov = wa + (size_t)P * CO + q * 32;
    #pragma unroll
    for (int j = 0; j < 8; ++j) *(float4*)(ov + j * 4) = acc[j];
}

// ---------------------------------------------------------------------------
// K3 (MFMA): out[b][c][p] = x + w_back . wa^T + b_back, computed as
// D[ch][px] = A(w_back[ch][k]) . B(wa[px][k])  -> stores coalesced along px.
// grid (NPIX/128, 2): blockIdx.y = channel half. BK=64, 2 k-steps.
// ---------------------------------------------------------------------------
__global__ __launch_bounds__(256) void k3_mfma(
    const float* __restrict__ wa, const float* __restrict__ wb,
    const float* __restrict__ bb_, const float* __restrict__ x,
    float* __restrict__ out)
{
    __shared__ char As[128 * 128];  // w_back tile [128 ch][64 k]
    __shared__ char Bs[128 * 128];  // wa tile    [128 px][64 k]

    const int t  = threadIdx.x;
    const int P0 = blockIdx.x * 128;
    const int cb = blockIdx.y * 128;
    const int b  = P0 / HW;
    const int p0 = P0 - b * HW;

    const int wid = t >> 6, lane = t & 63;
    const int wm = (wid & 1) * 64, wn = (wid >> 1) * 64;
    const int l15 = lane & 15, lg = lane >> 4;

    f32x4 acc[4][4] = {};

    for (int kt = 0; kt < CO; kt += 64) {
        if (kt) __syncthreads();
        #pragma unroll
        for (int it = 0; it < 8; ++it) {
            int kq = t & 15;
            int n  = (t >> 4) + it * 16;
            float4 w4 = *(const float4*)(wb + (size_t)(cb + n) * CO + kt + kq * 4);
            ushort4 v;
            v.x = f2bf(w4.x); v.y = f2bf(w4.y); v.z = f2bf(w4.z); v.w = f2bf(w4.w);
            *(ushort4*)(As + swz(n, kq * 8)) = v;
            float4 a4 = *(const float4*)(wa + (size_t)(P0 + n) * CO + kt + kq * 4);
            ushort4 u;
            u.x = f2bf(a4.x); u.y = f2bf(a4.y); u.z = f2bf(a4.z); u.w = f2bf(a4.w);
            *(ushort4*)(Bs + swz(n, kq * 8)) = u;
        }
        __syncthreads();
        #pragma unroll
        for (int ks = 0; ks < 2; ++ks) {
            const int kk2 = ks * 64 + lg * 16;
            short8v a[4], bq[4];
            #pragma unroll
            for (int mt = 0; mt < 4; ++mt)
                a[mt] = *(const short8v*)(As + swz(wm + mt * 16 + l15, kk2));
            #pragma unroll
            for (int nt = 0; nt < 4; ++nt)
                bq[nt] = *(const short8v*)(Bs + swz(wn + nt * 16 + l15, kk2));
            #pragma unroll
            for (int mt = 0; mt < 4; ++mt)
                #pragma unroll
                for (int nt = 0; nt < 4; ++nt)
                    acc[mt][nt] = __builtin_amdgcn_mfma_f32_16x16x32_bf16(
                        a[mt], bq[nt], acc[mt][nt], 0, 0, 0);
        }
    }

    // epilogue: D[ch][px]; residual + bias; 16-lane 64B coalesced along px
    #pragma unroll
    for (int mt = 0; mt < 4; ++mt)
        #pragma unroll
        for (int j = 0; j < 4; ++j) {
            int ch = cb + wm + mt * 16 + lg * 4 + j;
            size_t base = ((size_t)b * CIN + ch) * HW + p0;
            float bias = bb_[ch];
            #pragma unroll
            for (int nt = 0; nt < 4; ++nt) {
                int px = wn + nt * 16 + l15;
                out[base + px] = x[base + px] + acc[mt][nt][j] + bias;
            }
        }
}

extern "C" void kernel_launch(void* const* d_in, const int* in_sizes, int n_in,
                              void* d_out, int out_size, void* d_ws, size_t ws_size,
                              hipStream_t stream)
{
    const float* x  = (const float*)d_in[0];
    const float* wt = (const float*)d_in[1];
    const float* bt = (const float*)d_in[2];
    const float* wp = (const float*)d_in[3];
    const float* bp = (const float*)d_in[4];
    const float* wg = (const float*)d_in[5];
    const float* bg = (const float*)d_in[6];
    const float* wb = (const float*)d_in[7];
    const float* bb = (const float*)d_in[8];
    float* out = (float*)d_out;

    const size_t FEAT = (size_t)NPIX * CO;       // 9.4M floats = 37.75MB
    float* th = (float*)d_ws;
    float* ph = th + FEAT;
    float* gf = ph + FEAT;
    float* wa = (ws_size >= 4 * FEAT * sizeof(float)) ? (gf + FEAT) : th;

    hipLaunchKernelGGL(k1_mfma, dim3(NPIX / 128, 3), dim3(256), 0, stream,
                       x, wt, bt, wp, bp, wg, bg, th, ph, gf);
    hipLaunchKernelGGL(k_attn, dim3(NPIX / 64), dim3(256), 0, stream,
                       th, ph, gf, wa);
    hipLaunchKernelGGL(k3_mfma, dim3(NPIX / 128, 2), dim3(256), 0, stream,
                       wa, wb, bb, x, out);
}

// Round 4
// 234.386 us; speedup vs baseline: 2.6601x; 1.5295x over previous
//
#include <hip/hip_runtime.h>
#include <hip/hip_bf16.h>
#include <math.h>

#define HW   9216
#define WIMG 96
#define NPIX 73728  // 8 * 9216
#define CIN  256
#define CO   128

typedef __attribute__((ext_vector_type(8))) short short8v;        // 8 bf16 (4 VGPR)
typedef __attribute__((ext_vector_type(8))) unsigned short u16x8; // 8 bf16 raw
typedef __attribute__((ext_vector_type(4))) float f32x4;          // MFMA acc

__device__ __forceinline__ unsigned short f2bf(float f) {
    __hip_bfloat16 h = __float2bfloat16(f);
    return __builtin_bit_cast(unsigned short, h);
}
__device__ __forceinline__ float bf2f(unsigned short u) {
    unsigned v = ((unsigned)u) << 16;
    return __builtin_bit_cast(float, v);
}

// Swizzled byte offset into a [rows][64] bf16 LDS tile (128B rows).
// XOR row bits into the 16B-slot index: fragment reads <=2-way (free, m136).
__device__ __forceinline__ int swz(int row, int kk2 /*byte in row*/) {
    return (row * 128 + kk2) ^ ((row & 7) << 4);
}

// ---------------------------------------------------------------------------
// K1 (MFMA): feat[pixel][128] = bf16(x[pixel][:]) . bf16(W^T) + b  (bf16 out)
// Flat grid 1728 = 576 tiles x 3 maps. XCD-chunk swizzle, then nb = lb%3 so
// the 3 sibling blocks (same x-tile, different W) run adjacent on one XCD:
// x is HBM-read once, L2-hit twice.
// ---------------------------------------------------------------------------
__global__ __launch_bounds__(256) void k1_mfma(
    const float* __restrict__ x,
    const float* __restrict__ wt, const float* __restrict__ bt,
    const float* __restrict__ wp, const float* __restrict__ bp,
    const float* __restrict__ wg, const float* __restrict__ bg,
    unsigned short* __restrict__ th, unsigned short* __restrict__ ph,
    unsigned short* __restrict__ gf)
{
    __shared__ char As[128 * 128];  // [128 px][64 k] bf16, swizzled (16KB)
    __shared__ char Bs[128 * 128];  // [128 n ][64 k] bf16, swizzled (16KB)

    const int t   = threadIdx.x;
    const int bid = blockIdx.x;
    const int lb  = (bid & 7) * 216 + (bid >> 3);   // 1728 wg, 1728%8==0: bijective
    const int nb  = lb % 3;
    const int bx  = lb / 3;

    const float* W  = (nb == 0) ? wt : (nb == 1) ? wp : wg;
    const float* Bv = (nb == 0) ? bt : (nb == 1) ? bp : bg;
    unsigned short* O = (nb == 0) ? th : (nb == 1) ? ph : gf;

    const int P0 = bx * 128;               // 9216 % 128 == 0: no batch straddle
    const int b  = P0 / HW;
    const int p0 = P0 - b * HW;
    const float* xb = x + (size_t)b * CIN * HW + p0;

    const int wid = t >> 6, lane = t & 63;
    const int wm = (wid & 1) * 64, wn = (wid >> 1) * 64;
    const int l15 = lane & 15, lg = lane >> 4;

    f32x4 acc[4][4] = {};

    for (int kt = 0; kt < CIN; kt += 64) {
        if (kt) __syncthreads();
        // ---- stage A: x[kt+k][P0+pp] -> As[pp][k]  (transpose + cvt) ----
        #pragma unroll
        for (int it = 0; it < 8; ++it) {
            int kq = ((t >> 4) & 3) + (it & 3) * 4;                  // 0..15
            int pp = (t & 15) + ((t >> 6) << 4) + ((it >> 2) << 6);  // 0..127
            ushort4 v;
            v.x = f2bf(xb[(size_t)(kt + kq * 4 + 0) * HW + pp]);
            v.y = f2bf(xb[(size_t)(kt + kq * 4 + 1) * HW + pp]);
            v.z = f2bf(xb[(size_t)(kt + kq * 4 + 2) * HW + pp]);
            v.w = f2bf(xb[(size_t)(kt + kq * 4 + 3) * HW + pp]);
            *(ushort4*)(As + swz(pp, kq * 8)) = v;
        }
        // ---- stage B: W[n][kt+k] -> Bs[n][k] (float4 loads) ----
        #pragma unroll
        for (int it = 0; it < 8; ++it) {
            int kq = t & 15;
            int n  = (t >> 4) + it * 16;
            float4 w4 = *(const float4*)(W + (size_t)n * CIN + kt + kq * 4);
            ushort4 v;
            v.x = f2bf(w4.x); v.y = f2bf(w4.y); v.z = f2bf(w4.z); v.w = f2bf(w4.w);
            *(ushort4*)(Bs + swz(n, kq * 8)) = v;
        }
        __syncthreads();
        #pragma unroll
        for (int ks = 0; ks < 2; ++ks) {
            const int kk2 = ks * 64 + lg * 16;
            short8v a[4], bq[4];
            #pragma unroll
            for (int mt = 0; mt < 4; ++mt)
                a[mt] = *(const short8v*)(As + swz(wm + mt * 16 + l15, kk2));
            #pragma unroll
            for (int nt = 0; nt < 4; ++nt)
                bq[nt] = *(const short8v*)(Bs + swz(wn + nt * 16 + l15, kk2));
            #pragma unroll
            for (int mt = 0; mt < 4; ++mt)
                #pragma unroll
                for (int nt = 0; nt < 4; ++nt)
                    acc[mt][nt] = __builtin_amdgcn_mfma_f32_16x16x32_bf16(
                        a[mt], bq[nt], acc[mt][nt], 0, 0, 0);
        }
    }

    // ---- epilogue: D[row=(lg*4+j)][col=l15], add bias, bf16 store ----
    float bias[4];
    #pragma unroll
    for (int nt = 0; nt < 4; ++nt) bias[nt] = Bv[wn + nt * 16 + l15];
    #pragma unroll
    for (int mt = 0; mt < 4; ++mt)
        #pragma unroll
        for (int j = 0; j < 4; ++j) {
            size_t row = (size_t)(P0 + wm + mt * 16 + lg * 4 + j) * CO;
            #pragma unroll
            for (int nt = 0; nt < 4; ++nt)
                O[row + wn + nt * 16 + l15] = f2bf(acc[mt][nt][j] + bias[nt]);
        }
}

// ---------------------------------------------------------------------------
// K2: cosine-sim attention over 9 neighbors + weighted avg of g -> wa (bf16)
// Quad per pixel (32 ch/lane). XCD-chunk swizzle: each XCD sweeps exactly one
// batch image; 3-row gather window (~150KB) stays L2-resident.
// ---------------------------------------------------------------------------
__global__ __launch_bounds__(256) void k_attn(
    const unsigned short* __restrict__ th, const unsigned short* __restrict__ ph,
    const unsigned short* __restrict__ gf, unsigned short* __restrict__ wa)
{
    const int t   = threadIdx.x;
    const int bid = blockIdx.x;
    const int lb  = (bid & 7) * 144 + (bid >> 3);   // 1152 wg, bijective
    const int s = t >> 2, q = t & 3;
    const int P = lb * 64 + s;
    const int b = P / HW;
    const int p = P - b * HW;
    const int h = p / WIMG;
    const int w = p - h * WIMG;
    const size_t ib = (size_t)b * HW;

    const u16x8* tv = (const u16x8*)(th + (size_t)P * CO + q * 32);
    float T32[32];
    #pragma unroll
    for (int j = 0; j < 4; ++j) {
        u16x8 v = tv[j];
        #pragma unroll
        for (int e = 0; e < 8; ++e) T32[j * 8 + e] = bf2f(v[e]);
    }
    float tt = 0.f;
    #pragma unroll
    for (int k = 0; k < 32; ++k) tt = fmaf(T32[k], T32[k], tt);
    tt += __shfl_xor(tt, 1);
    tt += __shfl_xor(tt, 2);
    const float st = sqrtf(tt);

    float score[9];
    #pragma unroll
    for (int n = 0; n < 9; ++n) {
        int hh = h + n / 3 - 1; hh = hh < 0 ? 0 : (hh > 95 ? 95 : hh);
        int w2 = w + n % 3 - 1; w2 = w2 < 0 ? 0 : (w2 > 95 ? 95 : w2);
        const u16x8* pv = (const u16x8*)(ph + (ib + hh * WIMG + w2) * CO + q * 32);
        float d = 0.f, pp = 0.f;
        #pragma unroll
        for (int j = 0; j < 4; ++j) {
            u16x8 v = pv[j];
            #pragma unroll
            for (int e = 0; e < 8; ++e) {
                float f = bf2f(v[e]);
                d  = fmaf(T32[j * 8 + e], f, d);
                pp = fmaf(f, f, pp);
            }
        }
        d  += __shfl_xor(d, 1);  d  += __shfl_xor(d, 2);
        pp += __shfl_xor(pp, 1); pp += __shfl_xor(pp, 2);
        float den = fmaxf(sqrtf(pp) * st, 1e-8f);
        score[n] = d / den;
    }

    float mx = score[0];
    #pragma unroll
    for (int n = 1; n < 9; ++n) mx = fmaxf(mx, score[n]);
    float sum = 0.f;
    #pragma unroll
    for (int n = 0; n < 9; ++n) { score[n] = expf(score[n] - mx); sum += score[n]; }
    const float inv = 1.f / sum;

    float acc[32];
    #pragma unroll
    for (int k = 0; k < 32; ++k) acc[k] = 0.f;

    #pragma unroll
    for (int n = 0; n < 9; ++n) {
        int hh = h + n / 3 - 1; hh = hh < 0 ? 0 : (hh > 95 ? 95 : hh);
        int w2 = w + n % 3 - 1; w2 = w2 < 0 ? 0 : (w2 > 95 ? 95 : w2);
        const u16x8* gv = (const u16x8*)(gf + (ib + hh * WIMG + w2) * CO + q * 32);
        float a = score[n] * inv;
        #pragma unroll
        for (int j = 0; j < 4; ++j) {
            u16x8 v = gv[j];
            #pragma unroll
            for (int e = 0; e < 8; ++e)
                acc[j * 8 + e] = fmaf(a, bf2f(v[e]), acc[j * 8 + e]);
        }
    }

    u16x8* ov = (u16x8*)(wa + (size_t)P * CO + q * 32);
    #pragma unroll
    for (int j = 0; j < 4; ++j) {
        u16x8 o;
        #pragma unroll
        for (int e = 0; e < 8; ++e) o[e] = f2bf(acc[j * 8 + e]);
        ov[j] = o;
    }
}

// ---------------------------------------------------------------------------
// K3 (MFMA): out[b][c][p] = x + w_back . wa^T + b_back, D[ch][px] so stores
// are coalesced along px. wa is bf16 (cvt-free B staging). Flat grid 1152 =
// 576 tiles x 2 channel halves, XCD-chunk swizzle + sibling adjacency.
// ---------------------------------------------------------------------------
__global__ __launch_bounds__(256) void k3_mfma(
    const unsigned short* __restrict__ wa, const float* __restrict__ wb,
    const float* __restrict__ bb_, const float* __restrict__ x,
    float* __restrict__ out)
{
    __shared__ char As[128 * 128];  // w_back tile [128 ch][64 k]
    __shared__ char Bs[128 * 128];  // wa tile    [128 px][64 k]

    const int t   = threadIdx.x;
    const int bid = blockIdx.x;
    const int lb  = (bid & 7) * 144 + (bid >> 3);   // 1152 wg, bijective
    const int cb  = (lb & 1) * 128;
    const int P0  = (lb >> 1) * 128;
    const int b   = P0 / HW;
    const int p0  = P0 - b * HW;

    const int wid = t >> 6, lane = t & 63;
    const int wm = (wid & 1) * 64, wn = (wid >> 1) * 64;
    const int l15 = lane & 15, lg = lane >> 4;

    f32x4 acc[4][4] = {};

    for (int kt = 0; kt < CO; kt += 64) {
        if (kt) __syncthreads();
        // A: w_back[cb+n][kt..kt+63] fp32 -> bf16
        #pragma unroll
        for (int it = 0; it < 8; ++it) {
            int kq = t & 15;
            int n  = (t >> 4) + it * 16;
            float4 w4 = *(const float4*)(wb + (size_t)(cb + n) * CO + kt + kq * 4);
            ushort4 v;
            v.x = f2bf(w4.x); v.y = f2bf(w4.y); v.z = f2bf(w4.z); v.w = f2bf(w4.w);
            *(ushort4*)(As + swz(n, kq * 4 * 2)) = v;
        }
        // B: wa[P0+n][kt..kt+63] bf16 (raw 16B copies)
        #pragma unroll
        for (int it = 0; it < 4; ++it) {
            int kq = t & 7;
            int n  = (t >> 3) + it * 32;
            u16x8 u = *(const u16x8*)(wa + (size_t)(P0 + n) * CO + kt + kq * 8);
            *(u16x8*)(Bs + swz(n, kq * 16)) = u;
        }
        __syncthreads();
        #pragma unroll
        for (int ks = 0; ks < 2; ++ks) {
            const int kk2 = ks * 64 + lg * 16;
            short8v a[4], bq[4];
            #pragma unroll
            for (int mt = 0; mt < 4; ++mt)
                a[mt] = *(const short8v*)(As + swz(wm + mt * 16 + l15, kk2));
            #pragma unroll
            for (int nt = 0; nt < 4; ++nt)
                bq[nt] = *(const short8v*)(Bs + swz(wn + nt * 16 + l15, kk2));
            #pragma unroll
            for (int mt = 0; mt < 4; ++mt)
                #pragma unroll
                for (int nt = 0; nt < 4; ++nt)
                    acc[mt][nt] = __builtin_amdgcn_mfma_f32_16x16x32_bf16(
                        a[mt], bq[nt], acc[mt][nt], 0, 0, 0);
        }
    }

    // epilogue: D[ch][px]; residual + bias; coalesced along px
    #pragma unroll
    for (int mt = 0; mt < 4; ++mt)
        #pragma unroll
        for (int j = 0; j < 4; ++j) {
            int ch = cb + wm + mt * 16 + lg * 4 + j;
            size_t base = ((size_t)b * CIN + ch) * HW + p0;
            float bias = bb_[ch];
            #pragma unroll
            for (int nt = 0; nt < 4; ++nt) {
                int px = wn + nt * 16 + l15;
                out[base + px] = x[base + px] + acc[mt][nt][j] + bias;
            }
        }
}

extern "C" void kernel_launch(void* const* d_in, const int* in_sizes, int n_in,
                              void* d_out, int out_size, void* d_ws, size_t ws_size,
                              hipStream_t stream)
{
    const float* x  = (const float*)d_in[0];
    const float* wt = (const float*)d_in[1];
    const float* bt = (const float*)d_in[2];
    const float* wp = (const float*)d_in[3];
    const float* bp = (const float*)d_in[4];
    const float* wg = (const float*)d_in[5];
    const float* bg = (const float*)d_in[6];
    const float* wb = (const float*)d_in[7];
    const float* bb = (const float*)d_in[8];
    float* out = (float*)d_out;

    const size_t FEAT = (size_t)NPIX * CO;       // 9.4M elems; bf16 = 18.9MB each
    unsigned short* th = (unsigned short*)d_ws;
    unsigned short* ph = th + FEAT;
    unsigned short* gf = ph + FEAT;
    unsigned short* wa = gf + FEAT;              // 75.5MB total (ws held >=113MB in R2/R3)

    hipLaunchKernelGGL(k1_mfma, dim3(1728), dim3(256), 0, stream,
                       x, wt, bt, wp, bp, wg, bg, th, ph, gf);
    hipLaunchKernelGGL(k_attn, dim3(1152), dim3(256), 0, stream,
                       th, ph, gf, wa);
    hipLaunchKernelGGL(k3_mfma, dim3(1152), dim3(256), 0, stream,
                       wa, wb, bb, x, out);
}